// Round 4
// baseline (507.793 us; speedup 1.0000x reference)
//
#include <hip/hip_runtime.h>
#include <hip/hip_bf16.h>

#define GROUPS 12
#define POOL   64
#define TOPK   8
#define LAYERS 24
#define RANK   64
#define HID    1024
// weight_offset: [POOL, 2, HID*RANK*LAYERS]
#define D_LR   (HID * RANK * LAYERS)      // 1572864
#define POOL_STRIDE (2L * D_LR)           // 3145728

typedef __attribute__((ext_vector_type(8))) short bf16x8;
typedef __attribute__((ext_vector_type(4))) float f32x4;

__device__ __forceinline__ unsigned bfpack2(float lo, float hi) {
    float2 t; t.x = lo; t.y = hi;
    union { __hip_bfloat162 h; unsigned u; } cv;
    cv.h = __float22bfloat162_rn(t);
    return cv.u;
}

// XOR swizzle on the K-chunk index; verified conflict-free phases for both the
// b128 write pattern (col=4*lane+cc, chunk=rg) and read (col=base+fr, chunk=kk*4+kb)
__device__ __forceinline__ int sw_idx(int col, int chunk) {
    return chunk ^ (col & 7) ^ ((col >> 2) & 7);
}

// ---------------- Phase 1: routing (one block, 768 threads) ----------------
__global__ void routing_kernel(const float* __restrict__ q,     // [64, 768]
                               const float* __restrict__ keys,  // [12, 64, 64]
                               int* __restrict__ idx_out,       // [8]
                               float* __restrict__ w_out) {     // [8]
    __shared__ float invn[64][GROUPS];
    __shared__ float qbar[GROUPS][64];
    __shared__ float simg[GROUPS][64];
    const int t = threadIdx.x;

    {
        int b = t / GROUPS, g = t % GROUPS;
        const float* row = q + b * 768 + g * 64;
        float ss = 0.f;
        #pragma unroll 8
        for (int c = 0; c < 64; ++c) { float v = row[c]; ss = fmaf(v, v, ss); }
        invn[b][g] = 1.f / fmaxf(sqrtf(ss), 1e-8f);
    }
    __syncthreads();
    {
        int g = t >> 6, c = t & 63;
        float s = 0.f;
        for (int b = 0; b < 64; ++b) s = fmaf(q[b * 768 + g * 64 + c], invn[b][g], s);
        qbar[g][c] = s;
    }
    __syncthreads();
    {
        int g = t >> 6, p = t & 63;
        const float* krow = keys + (g * 64 + p) * 64;
        float ss = 0.f, dot = 0.f;
        #pragma unroll 8
        for (int c = 0; c < 64; ++c) {
            float v = krow[c];
            ss  = fmaf(v, v, ss);
            dot = fmaf(v, qbar[g][c], dot);
        }
        simg[g][p] = dot / fmaxf(sqrtf(ss), 1e-8f);
    }
    __syncthreads();
    if (t < 64) {
        float s = 0.f;
        for (int g = 0; g < GROUPS; ++g) s += simg[g][t];
        qbar[0][t] = s * (1.f / 768.f);
    }
    __syncthreads();
    if (t == 0) {
        float ms[POOL];
        for (int p = 0; p < POOL; ++p) ms[p] = qbar[0][p];
        float sum = 0.f;
        float vals[TOPK]; int ids[TOPK];
        for (int k = 0; k < TOPK; ++k) {
            float best = -3.4e38f; int bi = 0;
            for (int p = 0; p < POOL; ++p)
                if (ms[p] > best) { best = ms[p]; bi = p; }
            vals[k] = best; ids[k] = bi;
            ms[bi] = -3.4e38f; sum += best;
        }
        float inv = 1.f / (sum + 1e-9f);
        for (int k = 0; k < TOPK; ++k) { idx_out[k] = ids[k]; w_out[k] = vals[k] * inv; }
    }
}

// ---------------- Phase 2: bf16 MFMA GEMM, 256x256 tile, 16 waves ----------------
// 1024 threads; waves 0-7 stage A (w-scaled), waves 8-15 stage B; 4x4 wave grid,
// 64x64 C per wave; 2 blocks/CU co-resident (low VGPR) kills the dispatch tail
// and hides barrier/HBM latency via cross-block overlap.
__global__ __launch_bounds__(1024, 8) void lowrank_mfma_kernel(
        const float* __restrict__ wo,   // [64, 2, D_LR]
        const int*   __restrict__ idx,  // [8]
        const float* __restrict__ w,    // [8]
        float*       __restrict__ out)  // [24, 1024, 1024]
{
    __shared__ uint4 As4[256][8];   // [col][K-chunk of 8 bf16], swizzled
    __shared__ uint4 Bs4[256][8];
    __shared__ int   s_idx[TOPK];
    __shared__ float s_w[TOPK];

    const int tid = threadIdx.x;
    // bijective chunked XCD map: 48 consecutive tiles (3 layers) per XCD
    const int d    = blockIdx.x;
    const int orig = (d & 7) * 48 + (d >> 3);
    const int l    = orig >> 4;
    const int rem  = orig & 15;
    const int m0   = (rem >> 2) * 256;
    const int n0   = (rem & 3) * 256;

    if (tid < TOPK) { s_idx[tid] = idx[tid]; s_w[tid] = w[tid]; }
    __syncthreads();

    const int lane = tid & 63;
    const int wave = tid >> 6;
    const int wr = wave >> 2;      // 0..3 : 64-row band
    const int wc = wave & 3;       // 0..3 : 64-col band
    const int fr = lane & 15;
    const int kb = lane >> 4;

    // staging role: waves 0-7 -> A tile, waves 8-15 -> B tile
    const int  stb = (tid >= 512);
    const int  c4  = tid & 63;          // column quad (4 cols)
    const int  rg  = (tid >> 6) & 7;    // K-row octet = chunk
    const long stage_off = stb ? (long)D_LR : 0L;
    const int  base_col  = stb ? n0 : m0;

    f32x4 acc[4][4];
    #pragma unroll
    for (int i = 0; i < 4; ++i)
        #pragma unroll
        for (int j = 0; j < 4; ++j) acc[i][j] = (f32x4){0.f, 0.f, 0.f, 0.f};

    f32x4 raw[8];
    auto load_raw = [&](int s) {
        const long base = (long)s_idx[s] * POOL_STRIDE + (long)l * (RANK * HID) + stage_off;
        const float* p = wo + base + (long)(rg * 8) * HID + (base_col + c4 * 4);
        #pragma unroll
        for (int j = 0; j < 8; ++j) raw[j] = *(const f32x4*)(p + (long)j * HID);
    };

    load_raw(0);

    uint4 (*dst)[8] = stb ? Bs4 : As4;

    for (int s = 0; s < 8; ++s) {
        const float wn = stb ? 1.0f : s_w[s];
        // pack 8 K-rows x 4 cols -> 4 K-contiguous bf16x8 chunks (free transpose)
        #pragma unroll
        for (int cc = 0; cc < 4; ++cc) {
            const int col = c4 * 4 + cc;
            uint4 u;
            u.x = bfpack2(wn * raw[0][cc], wn * raw[1][cc]);
            u.y = bfpack2(wn * raw[2][cc], wn * raw[3][cc]);
            u.z = bfpack2(wn * raw[4][cc], wn * raw[5][cc]);
            u.w = bfpack2(wn * raw[6][cc], wn * raw[7][cc]);
            dst[col][sw_idx(col, rg)] = u;
        }
        __syncthreads();

        if (s < 7) load_raw(s + 1);   // VMEM issue overlaps MFMA cluster

        #pragma unroll
        for (int kk = 0; kk < 2; ++kk) {
            const int chunk = kk * 4 + kb;
            bf16x8 bfv[4];
            #pragma unroll
            for (int fj = 0; fj < 4; ++fj) {
                const int n = wc * 64 + fj * 16 + fr;
                bfv[fj] = *(const bf16x8*)&Bs4[n][sw_idx(n, chunk)];
            }
            #pragma unroll
            for (int fi = 0; fi < 4; ++fi) {
                const int m = wr * 64 + fi * 16 + fr;
                const bf16x8 af = *(const bf16x8*)&As4[m][sw_idx(m, chunk)];
                #pragma unroll
                for (int fj = 0; fj < 4; ++fj)
                    acc[fi][fj] = __builtin_amdgcn_mfma_f32_16x16x32_bf16(
                        af, bfv[fj], acc[fi][fj], 0, 0, 0);
            }
        }
        __syncthreads();
    }

    // epilogue: C/D layout n = lane&15, m = (lane>>4)*4 + v (validated round 1)
    float* o = out + (long)l * (1024 * 1024);
    #pragma unroll
    for (int fi = 0; fi < 4; ++fi) {
        #pragma unroll
        for (int fj = 0; fj < 4; ++fj) {
            const int n = n0 + wc * 64 + fj * 16 + fr;
            #pragma unroll
            for (int v = 0; v < 4; ++v) {
                const int m = m0 + wr * 64 + fi * 16 + kb * 4 + v;
                o[(long)m * 1024 + n] = acc[fi][fj][v];
            }
        }
    }
}

extern "C" void kernel_launch(void* const* d_in, const int* in_sizes, int n_in,
                              void* d_out, int out_size, void* d_ws, size_t ws_size,
                              hipStream_t stream) {
    const float* q    = (const float*)d_in[0];  // [64,768]
    const float* keys = (const float*)d_in[1];  // [1,12,64,64]
    const float* wo   = (const float*)d_in[2];  // [64,2,1572864]
    float* out = (float*)d_out;                 // [24,1024,1024]

    int*   idx = (int*)d_ws;
    float* w   = (float*)((char*)d_ws + 32);

    routing_kernel<<<1, 768, 0, stream>>>(q, keys, idx, w);

    lowrank_mfma_kernel<<<dim3(384, 1, 1), 1024, 0, stream>>>(wo, idx, w, out);
}

// Round 5
// 172.998 us; speedup vs baseline: 2.9353x; 2.9353x over previous
//
#include <hip/hip_runtime.h>
#include <hip/hip_bf16.h>

#define GROUPS 12
#define POOL   64
#define TOPK   8
#define LAYERS 24
#define RANK   64
#define HID    1024
// weight_offset: [POOL, 2, HID*RANK*LAYERS]
#define D_LR   (HID * RANK * LAYERS)      // 1572864
#define POOL_STRIDE (2L * D_LR)           // 3145728

typedef __attribute__((ext_vector_type(8))) short bf16x8;
typedef __attribute__((ext_vector_type(4))) float f32x4;

__device__ __forceinline__ unsigned bfpack2(float lo, float hi) {
    float2 t; t.x = lo; t.y = hi;
    union { __hip_bfloat162 h; unsigned u; } cv;
    cv.h = __float22bfloat162_rn(t);
    return cv.u;
}

// XOR swizzle on the K-chunk index; conflict-free for both the b128 write
// pattern (col=4*lane+cc, chunk=rg) and read (col=base+fr, chunk=kk*4+kb)
__device__ __forceinline__ int sw_idx(int col, int chunk) {
    return chunk ^ (col & 7) ^ ((col >> 2) & 7);
}

// ---------------- Phase 1: routing (one block, 768 threads) ----------------
__global__ void routing_kernel(const float* __restrict__ q,     // [64, 768]
                               const float* __restrict__ keys,  // [12, 64, 64]
                               int* __restrict__ idx_out,       // [8]
                               float* __restrict__ w_out) {     // [8]
    __shared__ float invn[64][GROUPS];
    __shared__ float qbar[GROUPS][64];
    __shared__ float simg[GROUPS][64];
    const int t = threadIdx.x;

    {
        int b = t / GROUPS, g = t % GROUPS;
        const float* row = q + b * 768 + g * 64;
        float ss = 0.f;
        #pragma unroll 8
        for (int c = 0; c < 64; ++c) { float v = row[c]; ss = fmaf(v, v, ss); }
        invn[b][g] = 1.f / fmaxf(sqrtf(ss), 1e-8f);
    }
    __syncthreads();
    {
        int g = t >> 6, c = t & 63;
        float s = 0.f;
        for (int b = 0; b < 64; ++b) s = fmaf(q[b * 768 + g * 64 + c], invn[b][g], s);
        qbar[g][c] = s;
    }
    __syncthreads();
    {
        int g = t >> 6, p = t & 63;
        const float* krow = keys + (g * 64 + p) * 64;
        float ss = 0.f, dot = 0.f;
        #pragma unroll 8
        for (int c = 0; c < 64; ++c) {
            float v = krow[c];
            ss  = fmaf(v, v, ss);
            dot = fmaf(v, qbar[g][c], dot);
        }
        simg[g][p] = dot / fmaxf(sqrtf(ss), 1e-8f);
    }
    __syncthreads();
    if (t < 64) {
        float s = 0.f;
        for (int g = 0; g < GROUPS; ++g) s += simg[g][t];
        qbar[0][t] = s * (1.f / 768.f);
    }
    __syncthreads();
    if (t == 0) {
        float ms[POOL];
        for (int p = 0; p < POOL; ++p) ms[p] = qbar[0][p];
        float sum = 0.f;
        float vals[TOPK]; int ids[TOPK];
        for (int k = 0; k < TOPK; ++k) {
            float best = -3.4e38f; int bi = 0;
            for (int p = 0; p < POOL; ++p)
                if (ms[p] > best) { best = ms[p]; bi = p; }
            vals[k] = best; ids[k] = bi;
            ms[bi] = -3.4e38f; sum += best;
        }
        float inv = 1.f / (sum + 1e-9f);
        for (int k = 0; k < TOPK; ++k) { idx_out[k] = ids[k]; w_out[k] = vals[k] * inv; }
    }
}

// -------- Phase 2: bf16 MFMA GEMM, 256x256 tile x2 per block, 16 waves --------
// 192 blocks; block = (layer l, m-panel m0, n-pair) -> computes tiles
// (l,m0,n0b) and (l,m0,n0b+256) sequentially (A panel L2-reused).
// Double-buffered LDS (128 KB), one barrier per K-slot, split staging roles.
__global__ __launch_bounds__(1024, 4) void lowrank_mfma_kernel(
        const float* __restrict__ wo,   // [64, 2, D_LR]
        const int*   __restrict__ idx,  // [8]
        const float* __restrict__ w,    // [8]
        float*       __restrict__ out)  // [24, 1024, 1024]
{
    __shared__ uint4 As4[2][256][8];   // [buf][col][K-chunk], swizzled
    __shared__ uint4 Bs4[2][256][8];
    __shared__ int   s_idx[TOPK];
    __shared__ float s_w[TOPK];

    const int tid = threadIdx.x;
    // XCD-grouped decomposition: d%8 = XCD (round-robin placement), 24 blocks
    // per XCD = 6 groups of 4 m-blocks; group shares its B panels via L2.
    const int d    = blockIdx.x;
    const int xcd  = d & 7;
    const int j    = d >> 3;            // 0..23 within XCD
    const int G    = xcd * 6 + (j >> 2);// global group 0..47
    const int m0   = (j & 3) * 256;
    const int l    = G >> 1;            // layer 0..23
    const int n0b  = (G & 1) * 512;     // n-pair base

    if (tid < TOPK) { s_idx[tid] = idx[tid]; s_w[tid] = w[tid]; }

    const int lane = tid & 63;
    const int wave = tid >> 6;
    const int wr = wave >> 2;      // 0..3 : 64-row band
    const int wc = wave & 3;       // 0..3 : 64-col band
    const int fr = lane & 15;
    const int kb = lane >> 4;

    // staging role: waves 0-7 -> A tile (w-scaled), waves 8-15 -> B tile
    const int  stb = (tid >= 512);
    const int  c4  = tid & 63;          // column quad (4 cols)
    const int  rg  = (tid >> 6) & 7;    // K-row octet = chunk
    const long stage_off = stb ? (long)D_LR : 0L;

    f32x4 acc[4][4];
    #pragma unroll
    for (int i = 0; i < 4; ++i)
        #pragma unroll
        for (int j2 = 0; j2 < 4; ++j2) acc[i][j2] = (f32x4){0.f, 0.f, 0.f, 0.f};

    __syncthreads();   // s_idx/s_w visible

    f32x4 raw[8];
    auto load_raw = [&](int ms) {      // ms = 0..15 macro-slot (tile*8 + slot)
        const int s = ms & 7;
        const int t = ms >> 3;
        const long base = (long)s_idx[s] * POOL_STRIDE + (long)l * (RANK * HID) + stage_off;
        const int  bc   = stb ? (n0b + t * 256) : m0;
        const float* p = wo + base + (long)(rg * 8) * HID + (bc + c4 * 4);
        #pragma unroll
        for (int r = 0; r < 8; ++r) raw[r] = *(const f32x4*)(p + (long)r * HID);
    };
    auto pack_write = [&](int ms) {    // write buffer ms&1, slot ms&7
        const float wn = stb ? 1.0f : s_w[ms & 7];
        uint4 (*dst)[8] = stb ? Bs4[ms & 1] : As4[ms & 1];
        #pragma unroll
        for (int cc = 0; cc < 4; ++cc) {
            const int col = c4 * 4 + cc;
            uint4 u;
            u.x = bfpack2(wn * raw[0][cc], wn * raw[1][cc]);
            u.y = bfpack2(wn * raw[2][cc], wn * raw[3][cc]);
            u.z = bfpack2(wn * raw[4][cc], wn * raw[5][cc]);
            u.w = bfpack2(wn * raw[6][cc], wn * raw[7][cc]);
            dst[col][sw_idx(col, rg)] = u;
        }
    };
    auto epilogue = [&](int t) {
        float* o = out + (long)l * (1024 * 1024);
        #pragma unroll
        for (int fi = 0; fi < 4; ++fi)
            #pragma unroll
            for (int fj = 0; fj < 4; ++fj) {
                const int n = n0b + t * 256 + wc * 64 + fj * 16 + fr;
                #pragma unroll
                for (int v = 0; v < 4; ++v) {
                    const int m = m0 + wr * 64 + fi * 16 + kb * 4 + v;
                    o[(long)m * 1024 + n] = acc[fi][fj][v];
                }
                acc[fi][fj] = (f32x4){0.f, 0.f, 0.f, 0.f};
            }
    };

    // prologue: stage macro-slot 0 into buffer 0
    load_raw(0);
    pack_write(0);
    __syncthreads();

    for (int ms = 0; ms < 16; ++ms) {
        const int cur = ms & 1;
        if (ms < 15) load_raw(ms + 1);      // global loads in flight under MFMA

        #pragma unroll
        for (int kk = 0; kk < 2; ++kk) {
            const int chunk = kk * 4 + kb;
            bf16x8 bfv[4];
            #pragma unroll
            for (int fj = 0; fj < 4; ++fj) {
                const int n = wc * 64 + fj * 16 + fr;
                bfv[fj] = *(const bf16x8*)&Bs4[cur][n][sw_idx(n, chunk)];
            }
            #pragma unroll
            for (int fi = 0; fi < 4; ++fi) {
                const int m = wr * 64 + fi * 16 + fr;
                const bf16x8 af = *(const bf16x8*)&As4[cur][m][sw_idx(m, chunk)];
                #pragma unroll
                for (int fj = 0; fj < 4; ++fj)
                    acc[fi][fj] = __builtin_amdgcn_mfma_f32_16x16x32_bf16(
                        af, bfv[fj], acc[fi][fj], 0, 0, 0);
            }
        }

        if (ms < 15) pack_write(ms + 1);    // into buffer cur^1 (no WAR hazard)
        __syncthreads();
        if (ms == 7) epilogue(0);           // tile 0 C-write overlaps tile-1 staging
    }
    epilogue(1);
}

extern "C" void kernel_launch(void* const* d_in, const int* in_sizes, int n_in,
                              void* d_out, int out_size, void* d_ws, size_t ws_size,
                              hipStream_t stream) {
    const float* q    = (const float*)d_in[0];  // [64,768]
    const float* keys = (const float*)d_in[1];  // [1,12,64,64]
    const float* wo   = (const float*)d_in[2];  // [64,2,1572864]
    float* out = (float*)d_out;                 // [24,1024,1024]

    int*   idx = (int*)d_ws;
    float* w   = (float*)((char*)d_ws + 32);

    routing_kernel<<<1, 768, 0, stream>>>(q, keys, idx, w);

    lowrank_mfma_kernel<<<dim3(192, 1, 1), 1024, 0, stream>>>(wo, idx, w, out);
}

// Round 6
// 80.017 us; speedup vs baseline: 6.3460x; 2.1620x over previous
//
#include <hip/hip_runtime.h>
#include <hip/hip_bf16.h>

#define GROUPS 12
#define POOL   64
#define TOPK   8
#define LAYERS 24
#define RANK   64
#define HID    1024
// weight_offset: [POOL, 2, HID*RANK*LAYERS]
#define D_LR   (HID * RANK * LAYERS)      // 1572864
#define POOL_STRIDE (2L * D_LR)           // 3145728

typedef __attribute__((ext_vector_type(8))) short bf16x8;
typedef __attribute__((ext_vector_type(4))) float f32x4;

__device__ __forceinline__ unsigned bfpack2(float lo, float hi) {
    float2 t; t.x = lo; t.y = hi;
    union { __hip_bfloat162 h; unsigned u; } cv;
    cv.h = __float22bfloat162_rn(t);
    return cv.u;
}

// XOR swizzle on the K-chunk index; conflict-free for both the b128 write
// pattern (col=4*lane+cc, chunk=rg) and read (col=base+fr, chunk=kk*4+kb)
__device__ __forceinline__ int sw_idx(int col, int chunk) {
    return chunk ^ (col & 7) ^ ((col >> 2) & 7);
}

// ---------------- Phase 1: routing (one block, 768 threads) ----------------
__global__ void routing_kernel(const float* __restrict__ q,     // [64, 768]
                               const float* __restrict__ keys,  // [12, 64, 64]
                               int* __restrict__ idx_out,       // [8]
                               float* __restrict__ w_out) {     // [8]
    __shared__ float invn[64][GROUPS];
    __shared__ float qbar[GROUPS][64];
    __shared__ float simg[GROUPS][64];
    const int t = threadIdx.x;

    {
        int b = t / GROUPS, g = t % GROUPS;
        const float* row = q + b * 768 + g * 64;
        float ss = 0.f;
        #pragma unroll 8
        for (int c = 0; c < 64; ++c) { float v = row[c]; ss = fmaf(v, v, ss); }
        invn[b][g] = 1.f / fmaxf(sqrtf(ss), 1e-8f);
    }
    __syncthreads();
    {
        int g = t >> 6, c = t & 63;
        float s = 0.f;
        for (int b = 0; b < 64; ++b) s = fmaf(q[b * 768 + g * 64 + c], invn[b][g], s);
        qbar[g][c] = s;
    }
    __syncthreads();
    {
        int g = t >> 6, p = t & 63;
        const float* krow = keys + (g * 64 + p) * 64;
        float ss = 0.f, dot = 0.f;
        #pragma unroll 8
        for (int c = 0; c < 64; ++c) {
            float v = krow[c];
            ss  = fmaf(v, v, ss);
            dot = fmaf(v, qbar[g][c], dot);
        }
        simg[g][p] = dot / fmaxf(sqrtf(ss), 1e-8f);
    }
    __syncthreads();
    if (t < 64) {
        float s = 0.f;
        for (int g = 0; g < GROUPS; ++g) s += simg[g][t];
        qbar[0][t] = s * (1.f / 768.f);
    }
    __syncthreads();
    if (t == 0) {
        float ms[POOL];
        for (int p = 0; p < POOL; ++p) ms[p] = qbar[0][p];
        float sum = 0.f;
        float vals[TOPK]; int ids[TOPK];
        for (int k = 0; k < TOPK; ++k) {
            float best = -3.4e38f; int bi = 0;
            for (int p = 0; p < POOL; ++p)
                if (ms[p] > best) { best = ms[p]; bi = p; }
            vals[k] = best; ids[k] = bi;
            ms[bi] = -3.4e38f; sum += best;
        }
        float inv = 1.f / (sum + 1e-9f);
        for (int k = 0; k < TOPK; ++k) { idx_out[k] = ids[k]; w_out[k] = vals[k] * inv; }
    }
}

// ---- Phase 2: bf16 MFMA GEMM, 256x256 tiles, 512 thr / 8 waves (proven shape) ----
// 256 blocks, 1-2 tiles each (384 total). Tile list is XCD-layer-ganged:
// phase 1: XCD x runs layers {2x, 2x+1} (16 tiles each, 16 CUs each) so the
// slot-synchronized 16-CU gang shares its A/B panel slices via that XCD's L2.
// phase 2: blocks i<16 of XCD x run layer 16+x. Deterministic single-round map.
__global__ __launch_bounds__(512, 2) void lowrank_mfma_kernel(
        const float* __restrict__ wo,   // [64, 2, D_LR]
        const int*   __restrict__ idx,  // [8]
        const float* __restrict__ w,    // [8]
        float*       __restrict__ out)  // [24, 1024, 1024]
{
    __shared__ uint4 As4[256][8];   // [col][K-chunk of 8 bf16], swizzled
    __shared__ uint4 Bs4[256][8];
    __shared__ int   s_idx[TOPK];
    __shared__ float s_w[TOPK];

    const int tid = threadIdx.x;
    const int b   = blockIdx.x;       // 0..255
    const int xcd = b & 7;            // assumed round-robin block->XCD
    const int i   = b >> 3;           // 0..31 within XCD

    // tile ids: T = l*16 + (m-idx*4 + n-idx)
    const int tile0 = (2 * xcd + (i >> 4)) * 16 + (i & 15);
    const int nt    = (i < 16) ? 2 : 1;
    const int tile1 = (16 + xcd) * 16 + i;   // valid only when nt==2

    if (tid < TOPK) { s_idx[tid] = idx[tid]; s_w[tid] = w[tid]; }
    __syncthreads();

    const int lane = tid & 63;
    const int wave = tid >> 6;
    const int wr = wave >> 2;      // 0..1 : 128-row band
    const int wc = wave & 3;       // 0..3 : 64-col band
    const int fr = lane & 15;
    const int kb = lane >> 4;

    const int c4 = lane;           // column quad 0..63 (4 cols each)
    const int rg = wave;           // K-row octet 0..7 = chunk

    f32x4 acc[8][4];
    #pragma unroll
    for (int p = 0; p < 8; ++p)
        #pragma unroll
        for (int q2 = 0; q2 < 4; ++q2) acc[p][q2] = (f32x4){0.f, 0.f, 0.f, 0.f};

    f32x4 araw[8], braw[8];

    auto load_raw = [&](int T, int s) {
        const int l   = T >> 4;
        const int rem = T & 15;
        const int m0  = (rem >> 2) * 256;
        const int n0  = (rem & 3) * 256;
        const long base = (long)s_idx[s] * POOL_STRIDE + (long)l * (RANK * HID);
        const float* pa = wo + base + (long)(rg * 8) * HID + (m0 + c4 * 4);
        const float* pb = wo + base + D_LR + (long)(rg * 8) * HID + (n0 + c4 * 4);
        #pragma unroll
        for (int j = 0; j < 8; ++j) araw[j] = *(const f32x4*)(pa + (long)j * HID);
        #pragma unroll
        for (int j = 0; j < 8; ++j) braw[j] = *(const f32x4*)(pb + (long)j * HID);
    };

    load_raw(tile0, 0);

    for (int ti = 0; ti < nt; ++ti) {
        const int T   = (ti == 0) ? tile0 : tile1;
        const int l   = T >> 4;
        const int rem = T & 15;
        const int m0  = (rem >> 2) * 256;
        const int n0  = (rem & 3) * 256;

        for (int s = 0; s < 8; ++s) {
            // pack previously-loaded slot s: 8 K-rows x 4 cols -> K-contig chunks
            const float wn = s_w[s];
            #pragma unroll
            for (int cc = 0; cc < 4; ++cc) {
                const int col = c4 * 4 + cc;
                uint4 ua, ub;
                ua.x = bfpack2(wn * araw[0][cc], wn * araw[1][cc]);
                ua.y = bfpack2(wn * araw[2][cc], wn * araw[3][cc]);
                ua.z = bfpack2(wn * araw[4][cc], wn * araw[5][cc]);
                ua.w = bfpack2(wn * araw[6][cc], wn * araw[7][cc]);
                ub.x = bfpack2(braw[0][cc], braw[1][cc]);
                ub.y = bfpack2(braw[2][cc], braw[3][cc]);
                ub.z = bfpack2(braw[4][cc], braw[5][cc]);
                ub.w = bfpack2(braw[6][cc], braw[7][cc]);
                const int cp = sw_idx(col, rg);
                As4[col][cp] = ua;
                Bs4[col][cp] = ub;
            }
            __syncthreads();

            // prefetch next slot (or next tile's slot 0) under the MFMA cluster
            if (s < 7)            load_raw(T, s + 1);
            else if (ti + 1 < nt) load_raw(tile1, 0);

            #pragma unroll
            for (int kk = 0; kk < 2; ++kk) {
                const int chunk = kk * 4 + kb;
                bf16x8 bfv[4];
                #pragma unroll
                for (int fj = 0; fj < 4; ++fj) {
                    const int n = wc * 64 + fj * 16 + fr;
                    bfv[fj] = *(const bf16x8*)&Bs4[n][sw_idx(n, chunk)];
                }
                #pragma unroll
                for (int fi = 0; fi < 8; ++fi) {
                    const int m = wr * 128 + fi * 16 + fr;
                    const bf16x8 af = *(const bf16x8*)&As4[m][sw_idx(m, chunk)];
                    #pragma unroll
                    for (int fj = 0; fj < 4; ++fj)
                        acc[fi][fj] = __builtin_amdgcn_mfma_f32_16x16x32_bf16(
                            af, bfv[fj], acc[fi][fj], 0, 0, 0);
                }
            }
            __syncthreads();
        }

        // epilogue: C/D layout n = lane&15, m = (lane>>4)*4 + v (validated)
        float* o = out + (long)l * (1024 * 1024);
        #pragma unroll
        for (int fi = 0; fi < 8; ++fi) {
            #pragma unroll
            for (int fj = 0; fj < 4; ++fj) {
                const int n = n0 + wc * 64 + fj * 16 + fr;
                #pragma unroll
                for (int v = 0; v < 4; ++v) {
                    const int m = m0 + wr * 128 + fi * 16 + kb * 4 + v;
                    o[(long)m * 1024 + n] = acc[fi][fj][v];
                }
                acc[fi][fj] = (f32x4){0.f, 0.f, 0.f, 0.f};
            }
        }
    }
}

extern "C" void kernel_launch(void* const* d_in, const int* in_sizes, int n_in,
                              void* d_out, int out_size, void* d_ws, size_t ws_size,
                              hipStream_t stream) {
    const float* q    = (const float*)d_in[0];  // [64,768]
    const float* keys = (const float*)d_in[1];  // [1,12,64,64]
    const float* wo   = (const float*)d_in[2];  // [64,2,1572864]
    float* out = (float*)d_out;                 // [24,1024,1024]

    int*   idx = (int*)d_ws;
    float* w   = (float*)((char*)d_ws + 32);

    routing_kernel<<<1, 768, 0, stream>>>(q, keys, idx, w);

    lowrank_mfma_kernel<<<dim3(256, 1, 1), 512, 0, stream>>>(wo, idx, w, out);
}